// Round 14
// baseline (576.361 us; speedup 1.0000x reference)
//
#include <hip/hip_runtime.h>
#include <hip/hip_bf16.h>
#include <math.h>

#define NH 4      // heads
#define OE 16     // OUT_E
#define ON 32     // OUT_N
#define INN 128   // IN_N
#define INE 32    // IN_E
#define HOE 64    // NH*OE
#define HON 128   // NH*ON

typedef __attribute__((ext_vector_type(8))) short bf16x8;
typedef __attribute__((ext_vector_type(4))) float f32x4;

__device__ __forceinline__ unsigned cvt_pk_bf16(float lo, float hi) {
    unsigned r;
    asm volatile("v_cvt_pk_bf16_f32 %0, %1, %2" : "=v"(r) : "v"(lo), "v"(hi));
    return r;
}

__device__ __forceinline__ unsigned short f32_to_bf16_bits(float x) {
    unsigned u = __float_as_uint(x);
    unsigned r = (u + 0x7fff + ((u >> 16) & 1)) >> 16;   // RNE
    return (unsigned short)r;
}

__device__ __forceinline__ float bf16_lo(unsigned w) { return __uint_as_float(w << 16); }
__device__ __forceinline__ float bf16_hi(unsigned w) { return __uint_as_float(w & 0xffff0000u); }

// sum over each 16-lane row via DPP row_ror (VALU only, no DS pipe)
__device__ __forceinline__ float rowsum16(float v) {
    int x;
    x = __builtin_amdgcn_update_dpp(0, __float_as_int(v), 0x128, 0xf, 0xf, true); // ror:8
    v += __int_as_float(x);
    x = __builtin_amdgcn_update_dpp(0, __float_as_int(v), 0x124, 0xf, 0xf, true); // ror:4
    v += __int_as_float(x);
    x = __builtin_amdgcn_update_dpp(0, __float_as_int(v), 0x122, 0xf, 0xf, true); // ror:2
    v += __int_as_float(x);
    x = __builtin_amdgcn_update_dpp(0, __float_as_int(v), 0x121, 0xf, 0xf, true); // ror:1
    v += __int_as_float(x);
    return v;
}

// ---------------- K0: zero int32 buffer ----------------
__global__ void k_zero_i32(int* __restrict__ p, int n) {
    int i = blockIdx.x * blockDim.x + threadIdx.x;
    int stride = gridDim.x * blockDim.x;
    for (; i < n; i += stride) p[i] = 0;
}

// ---------------- K0b: degree count ----------------
__global__ void k_count(const int* __restrict__ dst, int* __restrict__ count, int Ee) {
    int i = blockIdx.x * blockDim.x + threadIdx.x;
    int stride = gridDim.x * blockDim.x;
    for (; i < Ee; i += stride) atomicAdd(&count[dst[i]], 1);
}

// ---------------- K1: fused node GEMM via MFMA -------------------------------
// wave 0->fni bf16 pairs, 1->fnj bf16 pairs, 2->hproj lo bf16, 3->hproj hi bf16
__launch_bounds__(256)
__global__ void k_node_gemm(const float* __restrict__ nf,
                            const float* __restrict__ Wni,
                            const float* __restrict__ Wnj,
                            const float* __restrict__ Wnode,
                            unsigned* __restrict__ fni,
                            unsigned* __restrict__ fnj,
                            unsigned short* __restrict__ hproj,
                            int Nn) {
    int tid = threadIdx.x;
    int lane = tid & 63;
    int w = tid >> 6;
    int m = lane & 15;
    int kq = lane >> 4;
    const float* W; int wstride, wcoff;
    if (w == 0)      { W = Wni;   wstride = 64;  wcoff = 0;  }
    else if (w == 1) { W = Wnj;   wstride = 64;  wcoff = 0;  }
    else if (w == 2) { W = Wnode; wstride = 128; wcoff = 0;  }
    else             { W = Wnode; wstride = 128; wcoff = 64; }
    unsigned* outp = (w == 0) ? fni : fnj;
    int hsel = (w == 3);
    bf16x8 bv[4][4];
    #pragma unroll
    for (int k32 = 0; k32 < 4; k32++) {
        #pragma unroll
        for (int t = 0; t < 4; t++) {
            unsigned* bw = (unsigned*)&bv[k32][t];
            #pragma unroll
            for (int i = 0; i < 4; i++) {
                int k0 = k32 * 32 + kq * 8 + 2 * i;
                float lo = W[(size_t)k0 * wstride + wcoff + t * 16 + m];
                float hi = W[(size_t)(k0 + 1) * wstride + wcoff + t * 16 + m];
                bw[i] = cvt_pk_bf16(lo, hi);
            }
        }
    }
    int ngroups = (Nn + 15) >> 4;
    for (int g = blockIdx.x; g < ngroups; g += gridDim.x) {
        int r0 = g << 4;
        int ra = r0 + m; if (ra >= Nn) ra = Nn - 1;
        const float* ap = &nf[(size_t)ra * INN + kq * 8];
        bf16x8 av[4];
        #pragma unroll
        for (int k32 = 0; k32 < 4; k32++) {
            f32x4 a0 = *(const f32x4*)(ap + k32 * 32);
            f32x4 a1 = *(const f32x4*)(ap + k32 * 32 + 4);
            unsigned* aw = (unsigned*)&av[k32];
            aw[0] = cvt_pk_bf16(a0[0], a0[1]);
            aw[1] = cvt_pk_bf16(a0[2], a0[3]);
            aw[2] = cvt_pk_bf16(a1[0], a1[1]);
            aw[3] = cvt_pk_bf16(a1[2], a1[3]);
        }
        f32x4 c[4];
        #pragma unroll
        for (int t = 0; t < 4; t++) {
            c[t] = (f32x4){0.f, 0.f, 0.f, 0.f};
            #pragma unroll
            for (int k32 = 0; k32 < 4; k32++)
                c[t] = __builtin_amdgcn_mfma_f32_16x16x32_bf16(av[k32], bv[k32][t], c[t], 0, 0, 0);
        }
        #pragma unroll
        for (int j = 0; j < 4; j++) {
            int gr = r0 + kq * 4 + j;
            if (gr >= Nn) continue;
            if (w < 2) {
                outp[(size_t)gr * 32 + m]      = cvt_pk_bf16(c[0][j], c[2][j]);
                outp[(size_t)gr * 32 + m + 16] = cvt_pk_bf16(c[1][j], c[3][j]);
            } else {
                #pragma unroll
                for (int t = 0; t < 4; t++) {
                    int col = t * 16 + m;
                    hproj[(size_t)gr * 128 + 2 * col + hsel] = f32_to_bf16_bits(c[t][j]);
                }
            }
        }
    }
}

// ---------------- K3a: per-chunk exclusive scan (chunks of 256) --------------
__global__ void k_scan_chunks(const int* __restrict__ count,
                              int* __restrict__ chunkscan,
                              int* __restrict__ chunktot, int n) {
    __shared__ int tmp[256];
    int t = threadIdx.x;
    int i = blockIdx.x * 256 + t;
    int v = (i < n) ? count[i] : 0;
    tmp[t] = v;
    __syncthreads();
    for (int o = 1; o < 256; o <<= 1) {
        int x = (t >= o) ? tmp[t - o] : 0;
        __syncthreads();
        tmp[t] += x;
        __syncthreads();
    }
    if (i < n) chunkscan[i] = tmp[t] - v;
    if (t == 255) chunktot[blockIdx.x] = tmp[t];
}

// ---------------- K3b: scan chunk totals (single block) ----------------------
__global__ void k_scan_tot(const int* __restrict__ tot, int* __restrict__ base, int nc) {
    __shared__ int tmp[1024];
    int t = threadIdx.x;
    int v = (t < nc) ? tot[t] : 0;
    tmp[t] = v;
    __syncthreads();
    for (int o = 1; o < 1024; o <<= 1) {
        int x = (t >= o) ? tmp[t - o] : 0;
        __syncthreads();
        tmp[t] += x;
        __syncthreads();
    }
    if (t < nc) base[t] = tmp[t] - v;
}

// ---------------- K3c: final offsets ----------------------------------------
__global__ void k_offsets(const int* __restrict__ chunkscan,
                          const int* __restrict__ chunkbase,
                          int* __restrict__ offsets, int Nn, int Ee) {
    int i = blockIdx.x * blockDim.x + threadIdx.x;
    if (i < Nn) offsets[i] = chunkscan[i] + chunkbase[i >> 8];
    if (i == 0) offsets[Nn] = Ee;
}

// ---------------- K4: fill CSR edge lists (count reused as cursor) -----------
__global__ void k_fill(const int* __restrict__ dst,
                       const int* __restrict__ offsets,
                       int* __restrict__ count,     // holds degrees; decremented to 0
                       int* __restrict__ eids, int Ee) {
    int i = blockIdx.x * blockDim.x + threadIdx.x;
    int stride = gridDim.x * blockDim.x;
    for (; i < Ee; i += stride) {
        int d = dst[i];
        int p = atomicSub(&count[d], 1) - 1;   // reverse fill, order-invariant
        eids[offsets[d] + p] = i;
    }
}

// ---------------- K2: edge pass in CSR (dst-grouped) order -------------------
__launch_bounds__(256)
__global__ void k_edge(const float* __restrict__ efeats,
                       const int* __restrict__ src,
                       const int* __restrict__ dst,
                       const float* __restrict__ Wfij,   // [32][64]
                       const float* __restrict__ bias,   // [64]
                       const float* __restrict__ attn,   // [64]
                       const unsigned* __restrict__ fni, // [N][32] bf16 pairs
                       const unsigned* __restrict__ fnj, // [N][32] bf16 pairs
                       const int* __restrict__ eids,     // [E] CSR order
                       float* __restrict__ fout,         // [E,64] original order
                       float* __restrict__ exwsp,        // [E,4] f32, CSR order
                       int* __restrict__ srcp,           // [E]   CSR order
                       int Ee) {
    int tid = threadIdx.x;
    int lane = tid & 63;
    int m = lane & 15;
    int kq = lane >> 4;
    bf16x8 bv[4];
    #pragma unroll
    for (int t = 0; t < 4; t++) {
        unsigned* bw = (unsigned*)&bv[t];
        #pragma unroll
        for (int i = 0; i < 4; i++) {
            float lo = Wfij[(kq * 8 + 2 * i) * HOE + t * 16 + m];
            float hi = Wfij[(kq * 8 + 2 * i + 1) * HOE + t * 16 + m];
            bw[i] = cvt_pk_bf16(lo, hi);
        }
    }
    float bb[4], aa[4];
    #pragma unroll
    for (int t = 0; t < 4; t++) { bb[t] = bias[t * 16 + m]; aa[t] = attn[t * 16 + m]; }

    int wid = (blockIdx.x * 256 + tid) >> 6;
    int nw = (gridDim.x * 256) >> 6;
    int ntiles = (Ee + 15) >> 4;
    for (int T = wid; T < ntiles; T += nw) {
        int i0 = T << 4;
        int ia = i0 + m;
        int ra = eids[(ia < Ee) ? ia : (Ee - 1)];
        const float* ap = &efeats[(size_t)ra * INE + kq * 8];
        f32x4 a0 = __builtin_nontemporal_load((const f32x4*)ap);
        f32x4 a1 = __builtin_nontemporal_load((const f32x4*)(ap + 4));
        int eq[4], sj[4], dj[4]; bool ok[4];
        #pragma unroll
        for (int j = 0; j < 4; j++) {
            int pos = i0 + kq * 4 + j;
            ok[j] = pos < Ee;
            int pc = ok[j] ? pos : (Ee - 1);
            eq[j] = eids[pc];
            sj[j] = src[eq[j]];
            dj[j] = dst[eq[j]];
        }
        unsigned wi0[4], wi1[4], wj0[4], wj1[4];
        #pragma unroll
        for (int j = 0; j < 4; j++) {
            const unsigned* pi = &fni[(size_t)sj[j] * 32];
            const unsigned* pj = &fnj[(size_t)dj[j] * 32];
            wi0[j] = pi[m]; wi1[j] = pi[m + 16];
            wj0[j] = pj[m]; wj1[j] = pj[m + 16];
        }
        bf16x8 av;
        {
            unsigned* aw = (unsigned*)&av;
            aw[0] = cvt_pk_bf16(a0[0], a0[1]);
            aw[1] = cvt_pk_bf16(a0[2], a0[3]);
            aw[2] = cvt_pk_bf16(a1[0], a1[1]);
            aw[3] = cvt_pk_bf16(a1[2], a1[3]);
        }
        f32x4 c[4];
        #pragma unroll
        for (int t = 0; t < 4; t++) {
            c[t] = __builtin_amdgcn_mfma_f32_16x16x32_bf16(av, bv[t], (f32x4){0.f,0.f,0.f,0.f}, 0, 0, 0);
        }
        #pragma unroll
        for (int j = 0; j < 4; j++) {
            int pos = i0 + kq * 4 + j;
            float gni[4] = { bf16_lo(wi0[j]), bf16_lo(wi1[j]), bf16_hi(wi0[j]), bf16_hi(wi1[j]) };
            float gnj[4] = { bf16_lo(wj0[j]), bf16_lo(wj1[j]), bf16_hi(wj0[j]), bf16_hi(wj1[j]) };
            float pl[4];
            #pragma unroll
            for (int t = 0; t < 4; t++) {
                int col = t * 16 + m;
                float fv = c[t][j] + gni[t] + gnj[t] + bb[t];
                fv = fv > 0.f ? fv : 0.01f * fv;          // leaky relu
                if (ok[j]) fout[(size_t)eq[j] * HOE + col] = fv;
                pl[t] = rowsum16(fv * aa[t]);
            }
            if (ok[j] && m == 0) {
                float4 ex = make_float4(__expf(pl[0]), __expf(pl[1]),
                                        __expf(pl[2]), __expf(pl[3]));
                *(float4*)&exwsp[(size_t)pos * NH] = ex;
                srcp[pos] = sj[j];
            }
        }
    }
}

// ---------------- K5: node-centric softmax + aggregation ---------------------
__launch_bounds__(256)
__global__ void k_node_out(const int* __restrict__ offsets,
                           const int* __restrict__ srcp,
                           const float* __restrict__ exwsp,   // [E,4] CSR order
                           const unsigned* __restrict__ hproj2u, // [N,64] bf16 pairs
                           float* __restrict__ hout,          // [N,128]
                           int Nn) {
    int lane = threadIdx.x & 63;
    int n = (blockIdx.x * 256 + threadIdx.x) >> 6;
    if (n >= Nn) return;
    int o0 = __builtin_amdgcn_readfirstlane(offsets[n]);
    int o1 = __builtin_amdgcn_readfirstlane(offsets[n + 1]);
    int hi = lane >> 5;
    float s0 = 0.f, s1 = 0.f, s2 = 0.f, s3 = 0.f;
    float a0 = 0.f, a1 = 0.f;
    for (int i0 = o0; i0 < o1; i0 += 64) {
        int nb = min(64, o1 - i0);
        int vs = 0;
        if (lane < nb) vs = srcp[i0 + lane];               // coalesced
        for (int j0 = 0; j0 < nb; j0 += 8) {
            int cnt = nb - j0;
            float4 xx[8]; unsigned hp[8];
            #pragma unroll
            for (int u = 0; u < 8; u++) {
                int jj = j0 + ((u < cnt) ? u : cnt - 1);
                int s = __builtin_amdgcn_readlane(vs, jj);
                xx[u] = *(const float4*)&exwsp[(size_t)(i0 + jj) * NH];  // uniform addr
                hp[u] = hproj2u[(size_t)s * 64 + lane];
            }
            #pragma unroll
            for (int u = 0; u < 8; u++) {
                float4 x = xx[u];
                if (u >= cnt) x = make_float4(0.f, 0.f, 0.f, 0.f);
                s0 += x.x; s1 += x.y; s2 += x.z; s3 += x.w;
                float exl = (hi == 0) ? x.x : x.y;
                float exh = (hi == 0) ? x.z : x.w;
                a0 += bf16_lo(hp[u]) * exl;
                a1 += bf16_hi(hp[u]) * exh;
            }
        }
    }
    float r0 = s0 > 0.f ? 1.f / s0 : 0.f;
    float r1 = s1 > 0.f ? 1.f / s1 : 0.f;
    float r2 = s2 > 0.f ? 1.f / s2 : 0.f;
    float r3 = s3 > 0.f ? 1.f / s3 : 0.f;
    float rlo = (hi == 0) ? r0 : r1;
    float rhi = (hi == 0) ? r2 : r3;
    hout[(size_t)n * HON + lane] = a0 * rlo;
    hout[(size_t)n * HON + 64 + lane] = a1 * rhi;
}

// ---------------- launcher ----------------
extern "C" void kernel_launch(void* const* d_in, const int* in_sizes, int n_in,
                              void* d_out, int out_size, void* d_ws, size_t ws_size,
                              hipStream_t stream) {
    const float* n_feats = (const float*)d_in[0];
    const float* e_feats = (const float*)d_in[1];
    const int*   src     = (const int*)d_in[2];
    const int*   dst     = (const int*)d_in[3];
    const float* W_ni    = (const float*)d_in[4];
    const float* W_nj    = (const float*)d_in[5];
    const float* W_fij   = (const float*)d_in[6];
    const float* bias_e  = (const float*)d_in[7];
    const float* attn    = (const float*)d_in[8];
    const float* W_node  = (const float*)d_in[9];

    const int Nn = in_sizes[0] / INN;
    const int Ee = in_sizes[2];

    float* hout = (float*)d_out;                       // [N,128]
    float* fout = (float*)d_out + (size_t)Nn * HON;    // [E,64]

    char* ws = (char*)d_ws;
    size_t off = 0;
    auto alloc = [&](size_t bytes) {
        size_t o = off;
        off = (off + bytes + 255) & ~(size_t)255;
        return o;
    };
    size_t o_fni   = alloc((size_t)Nn * 32 * 4);       // bf16 pairs
    size_t o_fnj   = alloc((size_t)Nn * 32 * 4);       // bf16 pairs
    size_t o_hproj = alloc((size_t)Nn * HON * 2);      // bf16
    size_t o_exws  = alloc((size_t)Ee * NH * 4);       // f32 (R12-proven)
    size_t o_eids  = alloc((size_t)Ee * 4);
    size_t o_srcp  = alloc((size_t)Ee * 4);
    size_t o_cnt2  = alloc((size_t)2 * Nn * 4);        // count | (unused spare)
    size_t o_offs  = alloc((size_t)(Nn + 1) * 4);
    size_t o_cscan = alloc((size_t)Nn * 4);
    size_t o_cbase = alloc((size_t)1024 * 4);
    (void)ws_size;

    unsigned* fni = (unsigned*)(ws + o_fni);
    unsigned* fnj = (unsigned*)(ws + o_fnj);
    unsigned short* hproj = (unsigned short*)(ws + o_hproj);
    float* exwsp = (float*)(ws + o_exws);
    int* eids    = (int*)(ws + o_eids);
    int* srcp    = (int*)(ws + o_srcp);
    int* cnt2    = (int*)(ws + o_cnt2);
    int* count   = cnt2;
    int* offsets = (int*)(ws + o_offs);
    int* cscan   = (int*)(ws + o_cscan);
    int* cbase   = (int*)(ws + o_cbase);

    int nchunks = (Nn + 255) / 256;

    k_zero_i32<<<(Nn + 255) / 256, 256, 0, stream>>>(count, Nn);

    k_count<<<2048, 256, 0, stream>>>(dst, count, Ee);

    k_node_gemm<<<1024, 256, 0, stream>>>(
        n_feats, W_ni, W_nj, W_node, fni, fnj, hproj, Nn);

    k_scan_chunks<<<nchunks, 256, 0, stream>>>(count, cscan, cbase, Nn);
    k_scan_tot<<<1, 1024, 0, stream>>>(cbase, cbase, nchunks);
    k_offsets<<<(Nn + 255) / 256, 256, 0, stream>>>(cscan, cbase, offsets, Nn, Ee);

    k_fill<<<4096, 256, 0, stream>>>(dst, offsets, count, eids, Ee);

    k_edge<<<8192, 256, 0, stream>>>(
        e_feats, src, dst, W_fij, bias_e, attn, fni, fnj,
        eids, fout, exwsp, srcp, Ee);

    k_node_out<<<(Nn + 3) / 4, 256, 0, stream>>>(
        offsets, srcp, exwsp, (const unsigned*)hproj, hout, Nn);
}